// Round 2
// baseline (2441.262 us; speedup 1.0000x reference)
//
#include <hip/hip_runtime.h>
#include <stdint.h>

typedef __bf16 bf16_t;
typedef __bf16 bf16x8 __attribute__((ext_vector_type(8)));
typedef float floatx16 __attribute__((ext_vector_type(16)));
typedef unsigned int u32;
typedef unsigned long long u64;

#define NPROD 64   // Gx producer WGs
#define H1R   8    // h1 ring depth
#define SST   592  // L0 stage row stride (conflict-free b128 reads)
#define ZST   1104 // L1 z-tile row stride
#define FP    32   // flag padding: 32 u32 = 128 B per flag (one LLC line each)

struct KParams {
  const int* tok;
  const float* emb;
  const float* W1[4]; const float* b1[4];
  const float* W2[4]; const float* b2[4];
  const float* Wd; const float* bd; const float* Wout; const float* bout;
  float* out;
  u64* h1;           // ring: H1R x [64][128] tagged u64 (tag<<32 | bf16-pair)
  u64* h2;           // ring: 2   x [64][128] tagged u64
  u32* fl1;          // 32 flags (L1 step counters: h1-ring guard + head sync)
  u32* fl0g;         // 16 flags, producer-only mirror (Gx ring throttle)
  u32* pflags;       // 512 flags (producers -> L0)
  float* dstage;     // [64][128] fp32
  bf16_t* w1bf;      // [20][1024][16] fragment-ordered x-weights (bf16)
  float* gx;         // ring: R slabs of [64][1024] fp32
  int R;
};

__device__ __forceinline__ float sigf(float x) { return 1.f / (1.f + __expf(-x)); }
__device__ __forceinline__ float tanhf_fast(float x) { return 1.f - 2.f / (__expf(2.f * x) + 1.f); }

__device__ __forceinline__ u32 pack2(float a, float b) {
  uint16_t x = __builtin_bit_cast(uint16_t, (bf16_t)a);
  uint16_t y = __builtin_bit_cast(uint16_t, (bf16_t)b);
  return ((u32)y << 16) | (u32)x;
}
__device__ __forceinline__ float2 u2f2(u64 v) { union { u64 u; float2 f; } x; x.u = v; return x.f; }

// relaxed agent-scope ops: bypass L1/L2, coherent at LLC
__device__ __forceinline__ u32  ald32(const u32* p) { return __hip_atomic_load(p, __ATOMIC_RELAXED, __HIP_MEMORY_SCOPE_AGENT); }
__device__ __forceinline__ void ast32(u32* p, u32 v) { __hip_atomic_store(p, v, __ATOMIC_RELAXED, __HIP_MEMORY_SCOPE_AGENT); }
__device__ __forceinline__ u64  ald64(const u64* p) { return __hip_atomic_load(p, __ATOMIC_RELAXED, __HIP_MEMORY_SCOPE_AGENT); }
__device__ __forceinline__ void ast64(u64* p, u64 v) { __hip_atomic_store(p, v, __ATOMIC_RELAXED, __HIP_MEMORY_SCOPE_AGENT); }

// Bulk tag sweep: re-issue ALL stale elements each pass (converges in ~1 LLC RT,
// never serializes per-element round trips). Tag is the high 32 bits.
template<int N>
__device__ __forceinline__ void tag_wait(u64* tmp, const u64* hp, u32 need) {
  const int tid = threadIdx.x;
  bool ok = false;
  while (!ok) {
    ok = true;
#pragma unroll
    for (int t = 0; t < N; ++t)
      if ((u32)(tmp[t] >> 32) < need) { tmp[t] = ald64(hp + tid + 256 * t); ok = false; }
  }
  __atomic_signal_fence(__ATOMIC_ACQUIRE);
}

// Wave-parallel flag wait (wave 0 only, then __syncthreads by caller)
template<int NA, int NB>
__device__ __forceinline__ void waitcond(const u32* fa, u32 na, const u32* fb, u32 nb,
                                         const u32* pc, u32 nc) {
  const int lane = threadIdx.x & 63;
  const u32* ap; u32 need;
  if (lane < NA)           { ap = fa + lane * FP;        need = na; }
  else if (lane < NA + NB) { ap = fb + (lane - NA) * FP; need = nb; }
  else                     { ap = pc;                    need = nc; }
  while (!__all(ald32(ap) >= need)) {}
  __atomic_signal_fence(__ATOMIC_ACQUIRE);
}

// producer-side wait on the 16-flag mirror
__device__ __forceinline__ void waitg16(const u32* fa, u32 na) {
  const int lane = threadIdx.x & 63;
  const u32* ap = fa + (lane & 15) * FP;
  while (!__all(ald32(ap) >= na)) {}
  __atomic_signal_fence(__ATOMIC_ACQUIRE);
}

// ---------------- Layer 0: 16 WGs, each owns 16 units (64 gate cols) ----------
__device__ void run_l0(const KParams& p, int sub, char* abuf, float* cst, float* biasl)
{
  const int tid = threadIdx.x;
  const int w = tid >> 6, l = tid & 63, q = l >> 5, lr = l & 31;
  const int mh = w & 1, nh = w >> 1;

  if (tid < 64) biasl[tid] = p.b1[tid >> 4][sub * 16 + (tid & 15)];

  // W1 h-part rows 300..555 -> register B-fragments (reused 512x)
  const int c = nh * 32 + lr;
  const float* Wg = p.W1[c >> 4];
  const int un = sub * 16 + (c & 15);
  bf16x8 wf[16];
#pragma unroll
  for (int s2 = 0; s2 < 16; ++s2)
#pragma unroll
    for (int j = 0; j < 8; ++j) {
      int k = 16 * s2 + 8 * q + j;
      wf[s2][j] = (bf16_t)Wg[(300 + k) * 256 + un];
    }
  __syncthreads();

  float cs[2][2] = {{0.f, 0.f}, {0.f, 0.f}};

  for (int s = 0; s < 512; ++s) {
    // off-critical-path guards only: h1-ring reuse (L1 readers) + Gx ready
    u32 n1 = (s >= H1R) ? (u32)(s - (H1R - 1)) : 0u;
    if (w == 0) waitcond<32, 1>(p.fl1, n1, p.pflags + (size_t)s * FP, 1u,
                                p.pflags + (size_t)s * FP, 1u);
    __syncthreads();

    // Gx[s] loads issued with the stage loads (consumed at cell time)
    const float* slab = p.gx + (size_t)(s % p.R) * 65536u;
    u64 g[2][4];
#pragma unroll
    for (int kk = 0; kk < 2; ++kk) {
      int pp = tid + 256 * kk, b = pp >> 3, u2 = (pp & 7) * 2;
      const float* gb = slab + b * 1024 + sub * 64 + u2;
      g[kk][0] = ald64((const u64*)gb);
      g[kk][1] = ald64((const u64*)(gb + 16));
      g[kk][2] = ald64((const u64*)(gb + 32));
      g[kk][3] = ald64((const u64*)(gb + 48));
    }
    // tagged stage of h1[s-1] (self-publishing: tag s means h1[s-1] valid)
    {
      const u64* hp = p.h1 + (size_t)((s + H1R - 1) & (H1R - 1)) * 8192;
      u64 tmp[32];
#pragma unroll
      for (int t = 0; t < 32; ++t) tmp[t] = ald64(hp + tid + 256 * t);
      tag_wait<32>(tmp, hp, (u32)s);
#pragma unroll
      for (int t = 0; t < 32; ++t) {
        int i = tid + 256 * t, b = i >> 7, cc = i & 127;
        *(u32*)(abuf + b * SST + cc * 4) = (u32)tmp[t];
      }
    }
    __syncthreads();

    floatx16 acc;
#pragma unroll
    for (int e = 0; e < 16; ++e) acc[e] = 0.f;
    const char* arow = abuf + (mh * 32 + lr) * SST + q * 16;
#pragma unroll
    for (int s2 = 0; s2 < 16; ++s2) {
      bf16x8 af = *(const bf16x8*)(arow + 32 * s2);
      acc = __builtin_amdgcn_mfma_f32_32x32x16_bf16(af, wf[s2], acc, 0, 0, 0);
    }
#pragma unroll
    for (int e = 0; e < 16; ++e) {
      int ri = (e & 3) + 8 * (e >> 2) + 4 * q;
      cst[(mh * 32 + ri) * 68 + nh * 32 + lr] = acc[e];
    }
    __syncthreads();

    u64* hout = p.h1 + (size_t)(s & (H1R - 1)) * 8192;
#pragma unroll
    for (int kk = 0; kk < 2; ++kk) {
      int pp = tid + 256 * kk, b = pp >> 3, u2 = (pp & 7) * 2;
      float2 pf = *(float2*)&cst[b * 68 +      u2];
      float2 pi = *(float2*)&cst[b * 68 + 16 + u2];
      float2 pg = *(float2*)&cst[b * 68 + 32 + u2];
      float2 po = *(float2*)&cst[b * 68 + 48 + u2];
      float2 gf = u2f2(g[kk][0]), gi = u2f2(g[kk][1]);
      float2 gg = u2f2(g[kk][2]), go = u2f2(g[kk][3]);
      float hv[2];
#pragma unroll
      for (int j = 0; j < 2; ++j) {
        float fj = sigf((j ? pf.y : pf.x) + (j ? gf.y : gf.x) + biasl[u2 + j]);
        float ij = sigf((j ? pi.y : pi.x) + (j ? gi.y : gi.x) + biasl[16 + u2 + j]);
        float gj = tanhf_fast((j ? pg.y : pg.x) + (j ? gg.y : gg.x) + biasl[32 + u2 + j]);
        float oj = sigf((j ? po.y : po.x) + (j ? go.y : go.x) + biasl[48 + u2 + j]);
        float cn = fj * cs[kk][j] + ij * gj;
        cs[kk][j] = cn;
        hv[j] = oj * tanhf_fast(cn);
      }
      // data + step tag in ONE atomic word: visible == valid, no drain, no flag
      ast64(hout + b * 128 + sub * 8 + (u2 >> 1),
            ((u64)(u32)(s + 1) << 32) | (u64)pack2(hv[0], hv[1]));
    }
    // no end barrier: next-iteration bar0 provides the LDS fence
    if (tid == 0) ast32(&p.fl0g[sub * FP], (u32)(s + 1));
  }
}

// ---------------- Layer 1: 32 WGs, each 32 batch rows x 16 units, K=512 -------
// Pure tag-synced loop: zero flag waits, 2 barriers/step.
__device__ void run_l1(const KParams& p, int w2, char* zbuf, float* cst, float* biasl)
{
  const int tid = threadIdx.x;
  const int wv = tid >> 6, l = tid & 63, q = l >> 5, lr = l & 31;
  const int nh = wv & 1, kh = wv >> 1;
  const int bh = w2 & 1, sub1 = w2 >> 1;

  if (tid < 64) biasl[tid] = p.b2[tid >> 4][sub1 * 16 + (tid & 15)];

  const int c = nh * 32 + lr;
  const float* Wg = p.W2[c >> 4];
  const int un = sub1 * 16 + (c & 15);
  bf16x8 wf[16];   // this wave's K-half of W2 (z rows kh*256..+256)
#pragma unroll
  for (int s2 = 0; s2 < 16; ++s2)
#pragma unroll
    for (int j = 0; j < 8; ++j) {
      int k = kh * 256 + s2 * 16 + q * 8 + j;
      wf[s2][j] = (bf16_t)Wg[k * 256 + un];
    }
  __syncthreads();

  float cs2[2] = {0.f, 0.f};
  const int cb = tid >> 3, cu = (tid & 7) * 2;

  for (int s = 0; s < 512; ++s) {
    // tagged stage z = [h1[s] | h2[s-1]], rows bh*32..+32.
    // h2 issued first (the spinner), h1 second (L0 runs ~7 steps ahead).
    const u64* hp2 = p.h2 + (size_t)((s + 1) & 1) * 8192 + bh * 4096;
    const u64* hp1 = p.h1 + (size_t)(s & (H1R - 1)) * 8192 + bh * 4096;
    u64 t2[16], t1[16];
#pragma unroll
    for (int t = 0; t < 16; ++t) t2[t] = ald64(hp2 + tid + 256 * t);
#pragma unroll
    for (int t = 0; t < 16; ++t) t1[t] = ald64(hp1 + tid + 256 * t);
    tag_wait<16>(t1, hp1, (u32)(s + 1));
    tag_wait<16>(t2, hp2, (u32)s);
#pragma unroll
    for (int t = 0; t < 16; ++t) {
      int i = tid + 256 * t, r = i >> 7, cc = i & 127;
      *(u32*)(zbuf + r * ZST + cc * 4) = (u32)t1[t];
    }
#pragma unroll
    for (int t = 0; t < 16; ++t) {
      int i = tid + 256 * t, r = i >> 7, cc = i & 127;
      *(u32*)(zbuf + r * ZST + 512 + cc * 4) = (u32)t2[t];
    }
    __syncthreads();

    floatx16 acc;
#pragma unroll
    for (int e = 0; e < 16; ++e) acc[e] = 0.f;
    const char* arow = zbuf + lr * ZST + kh * 512 + q * 16;
#pragma unroll
    for (int s2 = 0; s2 < 16; ++s2) {
      bf16x8 af = *(const bf16x8*)(arow + 32 * s2);
      acc = __builtin_amdgcn_mfma_f32_32x32x16_bf16(af, wf[s2], acc, 0, 0, 0);
    }
#pragma unroll
    for (int e = 0; e < 16; ++e) {
      int ri = (e & 3) + 8 * (e >> 2) + 4 * q;
      cst[kh * 2176 + ri * 68 + nh * 32 + lr] = acc[e];
    }
    __syncthreads();

    // cell: sum the two K-half planes + bias; tagged h2 store self-publishes
    {
      float2 pf = *(float2*)&cst[cb * 68 +      cu];
      float2 pi = *(float2*)&cst[cb * 68 + 16 + cu];
      float2 pg = *(float2*)&cst[cb * 68 + 32 + cu];
      float2 po = *(float2*)&cst[cb * 68 + 48 + cu];
      float2 qf = *(float2*)&cst[2176 + cb * 68 +      cu];
      float2 qi = *(float2*)&cst[2176 + cb * 68 + 16 + cu];
      float2 qg = *(float2*)&cst[2176 + cb * 68 + 32 + cu];
      float2 qo = *(float2*)&cst[2176 + cb * 68 + 48 + cu];
      float hv[2];
#pragma unroll
      for (int j = 0; j < 2; ++j) {
        float fj = sigf((j ? pf.y + qf.y : pf.x + qf.x) + biasl[cu + j]);
        float ij = sigf((j ? pi.y + qi.y : pi.x + qi.x) + biasl[16 + cu + j]);
        float gj = tanhf_fast((j ? pg.y + qg.y : pg.x + qg.x) + biasl[32 + cu + j]);
        float oj = sigf((j ? po.y + qo.y : po.x + qo.x) + biasl[48 + cu + j]);
        float cn = fj * cs2[j] + ij * gj;
        cs2[j] = cn;
        hv[j] = oj * tanhf_fast(cn);
      }
      ast64(p.h2 + (size_t)(s & 1) * 8192 + (size_t)(bh * 32 + cb) * 128 + sub1 * 8 + (cu >> 1),
            ((u64)(u32)(s + 1) << 32) | (u64)pack2(hv[0], hv[1]));
    }
    // ring-guard heartbeat for L0 (off critical path; bar1 already proved h1[s] read)
    if (tid == 0) ast32(&p.fl1[w2 * FP], (u32)(s + 1));
  }

  // ---- dense head part 1: 4 cols of d = relu(h2_last @ Wd + bd) -------------
  {
    const u64* hp = p.h2 + 8192;   // h2[511] slab 1, tag 512
    u64 tmp[32];
#pragma unroll
    for (int t = 0; t < 32; ++t) tmp[t] = ald64(hp + tid + 256 * t);
    tag_wait<32>(tmp, hp, 512u);
#pragma unroll
    for (int t = 0; t < 32; ++t) {
      int i = tid + 256 * t, b = i >> 7, cc = i & 127;
      *(u32*)(zbuf + b * 520 + cc * 4) = (u32)tmp[t];
    }
  }
  __syncthreads();
  {
    int b = tid >> 2, cc = w2 * 4 + (tid & 3);
    const bf16_t* hrow = (const bf16_t*)(zbuf + b * 520);
    float a = p.bd[cc];
#pragma unroll 8
    for (int k = 0; k < 256; ++k) a += (float)hrow[k] * p.Wd[k * 128 + cc];
    ast32((u32*)&p.dstage[b * 128 + cc], __builtin_bit_cast(u32, fmaxf(a, 0.f)));
  }
  __syncthreads();                 // drains dstage scoped stores
  if (tid == 0) ast32(&p.fl1[w2 * FP], 513u);

  // ---- final: out = sigmoid(d @ Wout + bout), by L1 WG 0 --------------------
  if (w2 == 0) {
    if (wv == 0) waitcond<32, 0>(p.fl1, 513u, p.fl1, 0u, p.fl1, 0u);
    __syncthreads();
    if (tid < 64) {
      float a = p.bout[0];
#pragma unroll 8
      for (int cc = 0; cc < 128; ++cc) {
        u32 dv = ald32((u32*)&p.dstage[tid * 128 + cc]);
        a += __builtin_bit_cast(float, dv) * p.Wout[cc];
      }
      p.out[tid] = sigf(a);
    }
  }
}

// ---------------- Gx producers: Gx[s] = x_s @ W1x, K=300 (pad 320) -------------
__device__ void run_prod(const KParams& p, int pw, char* smem)
{
  const int tid = threadIdx.x;
  const int w = tid >> 6, l = tid & 63, q = l >> 5, lr = l & 31;
  const int mh = w & 1, chalf = w >> 1;
  const int R = p.R;

  for (int jj = 0; jj < 512 / NPROD; ++jj) {
    const int s = pw + NPROD * jj;
    if (s >= R) {  // ring throttle via producer-only mirror
      if (w == 0) waitg16(p.fl0g, (u32)(s - R + 1));
    }
    __syncthreads();
    {
      int b = tid >> 2, qq = tid & 3;
      int tokv = p.tok[b * 512 + s];
      const float4* src = (const float4*)(p.emb + (size_t)tokv * 300);
      char* dst = smem + b * 656;
      for (int j2 = qq; j2 < 75; j2 += 4) {
        float4 v = src[j2];
        *(u32*)(dst + 8 * j2)     = pack2(v.x, v.y);
        *(u32*)(dst + 8 * j2 + 4) = pack2(v.z, v.w);
      }
      for (int i = tid; i < 640; i += 256) {
        int bb = i / 10, cc2 = i % 10;
        *(u32*)(smem + bb * 656 + 600 + cc2 * 4) = 0u;
      }
    }
    __syncthreads();

    bf16x8 afr[20];
    const char* arow = smem + (mh * 32 + lr) * 656 + q * 16;
#pragma unroll
    for (int kt = 0; kt < 20; ++kt) afr[kt] = *(const bf16x8*)(arow + 32 * kt);

    float* slab = p.gx + (size_t)(s % R) * 65536u;
    for (int c2 = 0; c2 < 16; ++c2) {
      int n = (chalf * 16 + c2) * 32 + lr;
      floatx16 acc;
#pragma unroll
      for (int e = 0; e < 16; ++e) acc[e] = 0.f;
#pragma unroll
      for (int kt = 0; kt < 20; ++kt) {
        bf16x8 bf = ((const bf16x8*)p.w1bf)[(kt * 1024 + n) * 2 + q];
        acc = __builtin_amdgcn_mfma_f32_32x32x16_bf16(afr[kt], bf, acc, 0, 0, 0);
      }
#pragma unroll
      for (int e = 0; e < 16; ++e) {
        int ri = (e & 3) + 8 * (e >> 2) + 4 * q;
        ast32((u32*)(slab + (mh * 32 + ri) * 1024 + n), __builtin_bit_cast(u32, acc[e]));
      }
    }
    __syncthreads();                    // drains Gx scoped stores
    if (tid == 0) ast32(&p.pflags[s * FP], 1u);
  }
}

__global__ __launch_bounds__(256, 1) void lstm_main(KParams p)
{
  __shared__ __align__(16) char smem[64 * 656];   // L0 stage / L1 z-tile / producer buf / head
  __shared__ float cst[4352];                     // L0: [64][68]; L1: [2][32][68]
  __shared__ float biasl[64];
  const int wg = blockIdx.x;
  if (wg < 16)       run_l0(p, wg, smem, cst, biasl);
  else if (wg < 48)  run_l1(p, wg - 16, smem, cst, biasl);
  else               run_prod(p, wg - 48, smem);
}

// One-time: W1 x-part (rows 0..299, zero-pad to 320) -> bf16 fragment order.
__global__ void prep_w(KParams p) {
  int idx = blockIdx.x * 256 + threadIdx.x;
  if (idx >= 20 * 1024 * 16) return;
  int kk = idx & 15, n = (idx >> 4) & 1023, kt = idx >> 14;
  int k = kt * 16 + kk;
  int g = (n >> 4) & 3, su = n >> 6, u = n & 15;
  float v = (k < 300) ? p.W1[g][k * 256 + su * 16 + u] : 0.f;
  p.w1bf[idx] = (bf16_t)v;
}

// Zero tagged h rings + all flags (ws is re-poisoned before every launch).
// Zero tags = step 0 "valid with h=0", which is exactly the initial state.
__global__ void init_ws(u32* ws32) {
  int i = blockIdx.x * 256 + threadIdx.x;
  if (i < 181760) ws32[i] = 0u;   // [0, 727040): h1, h2, fl1, fl0g, pflags
}

extern "C" void kernel_launch(void* const* d_in, const int* in_sizes, int n_in,
                              void* d_out, int out_size, void* d_ws, size_t ws_size,
                              hipStream_t stream)
{
  KParams p;
  p.tok = (const int*)d_in[0];
  p.emb = (const float*)d_in[1];
  for (int g = 0; g < 4; ++g) {
    p.W1[g] = (const float*)d_in[2 + 2 * g];
    p.b1[g] = (const float*)d_in[3 + 2 * g];
    p.W2[g] = (const float*)d_in[10 + 2 * g];
    p.b2[g] = (const float*)d_in[11 + 2 * g];
  }
  p.Wd   = (const float*)d_in[18];
  p.bd   = (const float*)d_in[19];
  p.Wout = (const float*)d_in[20];
  p.bout = (const float*)d_in[21];
  p.out  = (float*)d_out;

  char* ws = (char*)d_ws;
  p.h1     = (u64*)ws;                    // 8 x 65536 B   -> 524288
  p.h2     = (u64*)(ws + 524288);         // 2 x 65536 B   -> 655360
  p.fl1    = (u32*)(ws + 655360);         // 32 x 128 B    -> 659456
  p.fl0g   = (u32*)(ws + 659456);         // 16 x 128 B    -> 661504
  p.pflags = (u32*)(ws + 661504);         // 512 x 128 B   -> 727040
  p.dstage = (float*)(ws + 727040);       // 32768 B       -> 759808
  p.w1bf   = (bf16_t*)(ws + 759808);      // 655360 B      -> 1415168
  p.gx     = (float*)(ws + 1415168);      // ring: R slabs of [64][1024] fp32

  long avail = (long)ws_size - 1415168L;
  int R = (int)(avail / 262144L);
  if (R > 64) R = 64;
  if (R < 1)  R = 1;
  p.R = R;

  hipLaunchKernelGGL(init_ws, dim3(710), dim3(256), 0, stream, (u32*)d_ws);
  hipLaunchKernelGGL(prep_w, dim3(1280), dim3(256), 0, stream, p);
  hipLaunchKernelGGL(lstm_main, dim3(16 + 32 + NPROD), dim3(256), 0, stream, p);
}

// Round 3
// 2243.034 us; speedup vs baseline: 1.0884x; 1.0884x over previous
//
#include <hip/hip_runtime.h>
#include <stdint.h>

typedef __bf16 bf16_t;
typedef __bf16 bf16x8 __attribute__((ext_vector_type(8)));
typedef float floatx16 __attribute__((ext_vector_type(16)));
typedef unsigned int u32;
typedef unsigned long long u64;

#define NPROD 64   // Gx producer WGs
#define H1R   8    // h1 ring depth (tagged slabs)
#define H2R   4    // h2 ring depth (tolerates skew-1 peers with margin)
#define SST   592  // L0 stage row stride (conflict-free b128 reads)
#define ZST   1104 // L1 z-tile row stride
#define FP    32   // flag padding: 32 u32 = 128 B per flag line

struct KParams {
  const int* tok;
  const float* emb;
  const float* W1[4]; const float* b1[4];
  const float* W2[4]; const float* b2[4];
  const float* Wd; const float* bd; const float* Wout; const float* bout;
  float* out;
  u64* h1;           // ring: H1R x [64][128] tagged u64 (tag<<32 | bf16-pair)
  u64* h2;           // ring: H2R x [64][128] tagged u64
  u32* fl1;          // 32 watermarks: L1 WG staged h1 up to step X (ring guard)
  u32* fl0g;         // 16 heartbeats: L0 consumed gx step X (producer throttle)
  u32* pflags;       // 512 flags (producers -> L0: gx[s] ready)
  float* dstage;     // [64][128] fp32
  bf16_t* w1bf;      // [20][1024][16] fragment-ordered x-weights (bf16)
  float* gx;         // ring: R slabs of [64][1024] fp32
  int R;
};

__device__ __forceinline__ float sigf(float x) { return 1.f / (1.f + __expf(-x)); }
__device__ __forceinline__ float tanhf_fast(float x) { return 1.f - 2.f / (__expf(2.f * x) + 1.f); }

__device__ __forceinline__ u32 pack2(float a, float b) {
  uint16_t x = __builtin_bit_cast(uint16_t, (bf16_t)a);
  uint16_t y = __builtin_bit_cast(uint16_t, (bf16_t)b);
  return ((u32)y << 16) | (u32)x;
}
__device__ __forceinline__ float2 u2f2(u64 v) { union { u64 u; float2 f; } x; x.u = v; return x.f; }

// relaxed agent-scope ops: bypass L1/L2, coherent at LLC/MALL
__device__ __forceinline__ u32  ald32(const u32* p) { return __hip_atomic_load(p, __ATOMIC_RELAXED, __HIP_MEMORY_SCOPE_AGENT); }
__device__ __forceinline__ void ast32(u32* p, u32 v) { __hip_atomic_store(p, v, __ATOMIC_RELAXED, __HIP_MEMORY_SCOPE_AGENT); }
__device__ __forceinline__ u64  ald64(const u64* p) { return __hip_atomic_load(p, __ATOMIC_RELAXED, __HIP_MEMORY_SCOPE_AGENT); }
__device__ __forceinline__ void ast64(u64* p, u64 v) { __hip_atomic_store(p, v, __ATOMIC_RELAXED, __HIP_MEMORY_SCOPE_AGENT); }

// ---------------- Layer 0: 16 WGs, each owns 16 units (64 gate cols) ----------
__device__ void run_l0(const KParams& p, int sub, char* abuf, float* cst, float* biasl)
{
  const int tid = threadIdx.x;
  const int w = tid >> 6, l = tid & 63, q = l >> 5, lr = l & 31;
  const int mh = w & 1, nh = w >> 1;

  if (tid < 64) biasl[tid] = p.b1[tid >> 4][sub * 16 + (tid & 15)];

  // W1 h-part rows 300..555 -> register B-fragments (reused 512x)
  const int c = nh * 32 + lr;
  const float* Wg = p.W1[c >> 4];
  const int un = sub * 16 + (c & 15);
  bf16x8 wf[16];
#pragma unroll
  for (int s2 = 0; s2 < 16; ++s2)
#pragma unroll
    for (int j = 0; j < 8; ++j) {
      int k = 16 * s2 + 8 * q + j;
      wf[s2][j] = (bf16_t)Wg[(300 + k) * 256 + un];
    }
  __syncthreads();

  float cs[2][2] = {{0.f, 0.f}, {0.f, 0.f}};

  for (int s = 0; s < 512; ++s) {
    __syncthreads();                                   // bar_A (LDS WAR fence)

    // 1) issue h1[s-1] tagged loads FIRST (the real dependency)
    const u64* hp = p.h1 + (size_t)((s + H1R - 1) & (H1R - 1)) * 8192;
    u64 tmp[32];
#pragma unroll
    for (int t = 0; t < 32; ++t) tmp[t] = ald64(hp + tid + 256 * t);

    // 2) guards polled by all waves (redundant, no cross-wave comm needed),
    //    overlapped with the in-flight h1 loads. Usually satisfied on pass 1.
    {
      u32 n1 = (s >= H1R) ? (u32)(s - (H1R - 1)) : 0u;
      const u32* gp; u32 gneed;
      if (l < 32) { gp = p.fl1 + l * FP;             gneed = n1; }   // ring guard
      else        { gp = p.pflags + (size_t)s * FP;  gneed = 1u; }   // gx ready
      while (!__all(ald32(gp) >= gneed)) {}
      __atomic_signal_fence(__ATOMIC_ACQUIRE);
    }

    // 3) h1 tag sweep: batched, wave-uniform, unconditional reloads
    for (;;) {
      bool ok = true;
#pragma unroll
      for (int t = 0; t < 32; ++t) ok &= ((u32)(tmp[t] >> 32) >= (u32)s);
      if (__all(ok)) break;
#pragma unroll
      for (int t = 0; t < 32; ++t) tmp[t] = ald64(hp + tid + 256 * t);
    }
    __atomic_signal_fence(__ATOMIC_ACQUIRE);

    // 4) gx[s] loads (pflags confirmed above); consumed at cell, ~stage+MFMA later
    const float* slab = p.gx + (size_t)(s % p.R) * 65536u;
    u64 g[2][4];
#pragma unroll
    for (int kk = 0; kk < 2; ++kk) {
      int pp = tid + 256 * kk, b = pp >> 3, u2 = (pp & 7) * 2;
      const float* gb = slab + b * 1024 + sub * 64 + u2;
      g[kk][0] = ald64((const u64*)gb);
      g[kk][1] = ald64((const u64*)(gb + 16));
      g[kk][2] = ald64((const u64*)(gb + 32));
      g[kk][3] = ald64((const u64*)(gb + 48));
    }

    // 5) stage h1 -> LDS
#pragma unroll
    for (int t = 0; t < 32; ++t) {
      int i = tid + 256 * t, b = i >> 7, cc = i & 127;
      *(u32*)(abuf + b * SST + cc * 4) = (u32)tmp[t];
    }
    __syncthreads();                                   // bar_B

    floatx16 acc;
#pragma unroll
    for (int e = 0; e < 16; ++e) acc[e] = 0.f;
    const char* arow = abuf + (mh * 32 + lr) * SST + q * 16;
#pragma unroll
    for (int s2 = 0; s2 < 16; ++s2) {
      bf16x8 af = *(const bf16x8*)(arow + 32 * s2);
      acc = __builtin_amdgcn_mfma_f32_32x32x16_bf16(af, wf[s2], acc, 0, 0, 0);
    }
#pragma unroll
    for (int e = 0; e < 16; ++e) {
      int ri = (e & 3) + 8 * (e >> 2) + 4 * q;
      cst[(mh * 32 + ri) * 68 + nh * 32 + lr] = acc[e];
    }
    __syncthreads();                                   // bar_C

    u64* hout = p.h1 + (size_t)(s & (H1R - 1)) * 8192;
#pragma unroll
    for (int kk = 0; kk < 2; ++kk) {
      int pp = tid + 256 * kk, b = pp >> 3, u2 = (pp & 7) * 2;
      float2 pf = *(float2*)&cst[b * 68 +      u2];
      float2 pi = *(float2*)&cst[b * 68 + 16 + u2];
      float2 pg = *(float2*)&cst[b * 68 + 32 + u2];
      float2 po = *(float2*)&cst[b * 68 + 48 + u2];
      float2 gf = u2f2(g[kk][0]), gi = u2f2(g[kk][1]);
      float2 gg = u2f2(g[kk][2]), go = u2f2(g[kk][3]);
      float hv[2];
#pragma unroll
      for (int j = 0; j < 2; ++j) {
        float fj = sigf((j ? pf.y : pf.x) + (j ? gf.y : gf.x) + biasl[u2 + j]);
        float ij = sigf((j ? pi.y : pi.x) + (j ? gi.y : gi.x) + biasl[16 + u2 + j]);
        float gj = tanhf_fast((j ? pg.y : pg.x) + (j ? gg.y : gg.x) + biasl[32 + u2 + j]);
        float oj = sigf((j ? po.y : po.x) + (j ? go.y : go.x) + biasl[48 + u2 + j]);
        float cn = fj * cs[kk][j] + ij * gj;
        cs[kk][j] = cn;
        hv[j] = oj * tanhf_fast(cn);
      }
      // data + tag in one atomic word: visible == valid (no drain, no flag)
      ast64(hout + b * 128 + sub * 8 + (u2 >> 1),
            ((u64)(u32)(s + 1) << 32) | (u64)pack2(hv[0], hv[1]));
    }
    // producer throttle heartbeat (slack ~R steps; peers within 1 barrier)
    if (tid == 0) ast32(&p.fl0g[sub * FP], (u32)(s + 1));
  }
}

// ---------------- Layer 1: 32 WGs, each 32 batch rows x 16 units, K=512 -------
// Zero flags on the critical path: one combined tag sweep per step, 3 barriers.
__device__ void run_l1(const KParams& p, int w2, char* zbuf, float* cst, float* biasl)
{
  const int tid = threadIdx.x;
  const int wv = tid >> 6, l = tid & 63, q = l >> 5, lr = l & 31;
  const int nh = wv & 1, kh = wv >> 1;
  const int bh = w2 & 1, sub1 = w2 >> 1;

  if (tid < 64) biasl[tid] = p.b2[tid >> 4][sub1 * 16 + (tid & 15)];

  const int c = nh * 32 + lr;
  const float* Wg = p.W2[c >> 4];
  const int un = sub1 * 16 + (c & 15);
  bf16x8 wf[16];   // this wave's K-half of W2 (z rows kh*256..+256)
#pragma unroll
  for (int s2 = 0; s2 < 16; ++s2)
#pragma unroll
    for (int j = 0; j < 8; ++j) {
      int k = kh * 256 + s2 * 16 + q * 8 + j;
      wf[s2][j] = (bf16_t)Wg[k * 256 + un];
    }
  __syncthreads();

  float cs2[2] = {0.f, 0.f};
  const int cb = tid >> 3, cu = (tid & 7) * 2;

  for (int s = 0; s < 512; ++s) {
    __syncthreads();                                   // bar_A

    // issue h1[s] + h2[s-1] tagged loads together, then ONE combined sweep
    const u64* hp1 = p.h1 + (size_t)(s & (H1R - 1)) * 8192 + bh * 4096;
    const u64* hp2 = p.h2 + (size_t)((s + H2R - 1) & (H2R - 1)) * 8192 + bh * 4096;
    u64 t1[16], t2[16];
#pragma unroll
    for (int t = 0; t < 16; ++t) t1[t] = ald64(hp1 + tid + 256 * t);
#pragma unroll
    for (int t = 0; t < 16; ++t) t2[t] = ald64(hp2 + tid + 256 * t);
    for (;;) {
      bool ok = true;
#pragma unroll
      for (int t = 0; t < 16; ++t) ok &= ((u32)(t1[t] >> 32) >= (u32)(s + 1));
#pragma unroll
      for (int t = 0; t < 16; ++t) ok &= ((u32)(t2[t] >> 32) >= (u32)s);
      if (__all(ok)) break;
#pragma unroll
      for (int t = 0; t < 16; ++t) t1[t] = ald64(hp1 + tid + 256 * t);
#pragma unroll
      for (int t = 0; t < 16; ++t) t2[t] = ald64(hp2 + tid + 256 * t);
    }
    __atomic_signal_fence(__ATOMIC_ACQUIRE);

    // stage z = [h1[s] | h2[s-1]]
#pragma unroll
    for (int t = 0; t < 16; ++t) {
      int i = tid + 256 * t, r = i >> 7, cc = i & 127;
      *(u32*)(zbuf + r * ZST + cc * 4) = (u32)t1[t];
    }
#pragma unroll
    for (int t = 0; t < 16; ++t) {
      int i = tid + 256 * t, r = i >> 7, cc = i & 127;
      *(u32*)(zbuf + r * ZST + 512 + cc * 4) = (u32)t2[t];
    }
    __syncthreads();                                   // bar_B
    // staged-watermark for L0's ring guard (all waves provably past the sweep)
    if (tid == 0) ast32(&p.fl1[w2 * FP], (u32)(s + 1));

    floatx16 acc;
#pragma unroll
    for (int e = 0; e < 16; ++e) acc[e] = 0.f;
    const char* arow = zbuf + lr * ZST + kh * 512 + q * 16;
#pragma unroll
    for (int s2 = 0; s2 < 16; ++s2) {
      bf16x8 af = *(const bf16x8*)(arow + 32 * s2);
      acc = __builtin_amdgcn_mfma_f32_32x32x16_bf16(af, wf[s2], acc, 0, 0, 0);
    }
#pragma unroll
    for (int e = 0; e < 16; ++e) {
      int ri = (e & 3) + 8 * (e >> 2) + 4 * q;
      cst[kh * 2176 + ri * 68 + nh * 32 + lr] = acc[e];
    }
    __syncthreads();                                   // bar_C

    // cell: sum the two K-half planes + bias; tagged h2 store self-publishes
    {
      float2 pf = *(float2*)&cst[cb * 68 +      cu];
      float2 pi = *(float2*)&cst[cb * 68 + 16 + cu];
      float2 pg = *(float2*)&cst[cb * 68 + 32 + cu];
      float2 po = *(float2*)&cst[cb * 68 + 48 + cu];
      float2 qf = *(float2*)&cst[2176 + cb * 68 +      cu];
      float2 qi = *(float2*)&cst[2176 + cb * 68 + 16 + cu];
      float2 qg = *(float2*)&cst[2176 + cb * 68 + 32 + cu];
      float2 qo = *(float2*)&cst[2176 + cb * 68 + 48 + cu];
      float hv[2];
#pragma unroll
      for (int j = 0; j < 2; ++j) {
        float fj = sigf((j ? pf.y + qf.y : pf.x + qf.x) + biasl[cu + j]);
        float ij = sigf((j ? pi.y + qi.y : pi.x + qi.x) + biasl[16 + cu + j]);
        float gj = tanhf_fast((j ? pg.y + qg.y : pg.x + qg.x) + biasl[32 + cu + j]);
        float oj = sigf((j ? po.y + qo.y : po.x + qo.x) + biasl[48 + cu + j]);
        float cn = fj * cs2[j] + ij * gj;
        cs2[j] = cn;
        hv[j] = oj * tanhf_fast(cn);
      }
      ast64(p.h2 + (size_t)(s & (H2R - 1)) * 8192 + (size_t)(bh * 32 + cb) * 128
                 + sub1 * 8 + (cu >> 1),
            ((u64)(u32)(s + 1) << 32) | (u64)pack2(hv[0], hv[1]));
    }
  }

  // ---- dense head part 1: 4 cols of d = relu(h2_last @ Wd + bd) -------------
  {
    const u64* hp = p.h2 + (size_t)(511 & (H2R - 1)) * 8192;   // h2[511], tag 512
    u64 tmp[32];
#pragma unroll
    for (int t = 0; t < 32; ++t) tmp[t] = ald64(hp + tid + 256 * t);
    for (;;) {
      bool ok = true;
#pragma unroll
      for (int t = 0; t < 32; ++t) ok &= ((u32)(tmp[t] >> 32) >= 512u);
      if (__all(ok)) break;
#pragma unroll
      for (int t = 0; t < 32; ++t) tmp[t] = ald64(hp + tid + 256 * t);
    }
    __atomic_signal_fence(__ATOMIC_ACQUIRE);
#pragma unroll
    for (int t = 0; t < 32; ++t) {
      int i = tid + 256 * t, b = i >> 7, cc = i & 127;
      *(u32*)(zbuf + b * 520 + cc * 4) = (u32)tmp[t];
    }
  }
  __syncthreads();
  {
    int b = tid >> 2, cc = w2 * 4 + (tid & 3);
    const bf16_t* hrow = (const bf16_t*)(zbuf + b * 520);
    float a = p.bd[cc];
#pragma unroll 8
    for (int k = 0; k < 256; ++k) a += (float)hrow[k] * p.Wd[k * 128 + cc];
    ast32((u32*)&p.dstage[b * 128 + cc], __builtin_bit_cast(u32, fmaxf(a, 0.f)));
  }
  __syncthreads();                 // drains dstage scoped stores (vmcnt0+barrier)
  if (tid == 0) ast32(&p.fl1[w2 * FP], 600u);

  // ---- final: out = sigmoid(d @ Wout + bout), by L1 WG 0 --------------------
  if (w2 == 0) {
    if (wv == 0) {
      const int lane = l;
      const u32* ap = p.fl1 + (lane & 31) * FP;
      while (!__all(ald32(ap) >= 600u)) {}
      __atomic_signal_fence(__ATOMIC_ACQUIRE);
    }
    __syncthreads();
    if (tid < 64) {
      float a = p.bout[0];
#pragma unroll 8
      for (int cc = 0; cc < 128; ++cc) {
        u32 dv = ald32((u32*)&p.dstage[tid * 128 + cc]);
        a += __builtin_bit_cast(float, dv) * p.Wout[cc];
      }
      p.out[tid] = sigf(a);
    }
  }
}

// ---------------- Gx producers: Gx[s] = x_s @ W1x, K=300 (pad 320) -------------
__device__ void run_prod(const KParams& p, int pw, char* smem)
{
  const int tid = threadIdx.x;
  const int w = tid >> 6, l = tid & 63, q = l >> 5, lr = l & 31;
  const int mh = w & 1, chalf = w >> 1;
  const int R = p.R;

  for (int jj = 0; jj < 512 / NPROD; ++jj) {
    const int s = pw + NPROD * jj;
    if (s >= R) {  // ring throttle via producer-only mirror
      if (w == 0) {
        const u32* ap = p.fl0g + (l & 15) * FP;
        while (!__all(ald32(ap) >= (u32)(s - R + 1))) {}
        __atomic_signal_fence(__ATOMIC_ACQUIRE);
      }
    }
    __syncthreads();
    {
      int b = tid >> 2, qq = tid & 3;
      int tokv = p.tok[b * 512 + s];
      const float4* src = (const float4*)(p.emb + (size_t)tokv * 300);
      char* dst = smem + b * 656;
      for (int j2 = qq; j2 < 75; j2 += 4) {
        float4 v = src[j2];
        *(u32*)(dst + 8 * j2)     = pack2(v.x, v.y);
        *(u32*)(dst + 8 * j2 + 4) = pack2(v.z, v.w);
      }
      for (int i = tid; i < 640; i += 256) {
        int bb = i / 10, cc2 = i % 10;
        *(u32*)(smem + bb * 656 + 600 + cc2 * 4) = 0u;
      }
    }
    __syncthreads();

    bf16x8 afr[20];
    const char* arow = smem + (mh * 32 + lr) * 656 + q * 16;
#pragma unroll
    for (int kt = 0; kt < 20; ++kt) afr[kt] = *(const bf16x8*)(arow + 32 * kt);

    float* slab = p.gx + (size_t)(s % R) * 65536u;
    for (int c2 = 0; c2 < 16; ++c2) {
      int n = (chalf * 16 + c2) * 32 + lr;
      floatx16 acc;
#pragma unroll
      for (int e = 0; e < 16; ++e) acc[e] = 0.f;
#pragma unroll
      for (int kt = 0; kt < 20; ++kt) {
        bf16x8 bf = ((const bf16x8*)p.w1bf)[(kt * 1024 + n) * 2 + q];
        acc = __builtin_amdgcn_mfma_f32_32x32x16_bf16(afr[kt], bf, acc, 0, 0, 0);
      }
#pragma unroll
      for (int e = 0; e < 16; ++e) {
        int ri = (e & 3) + 8 * (e >> 2) + 4 * q;
        ast32((u32*)(slab + (mh * 32 + ri) * 1024 + n), __builtin_bit_cast(u32, acc[e]));
      }
    }
    __syncthreads();                    // drains Gx scoped stores (vmcnt0+barrier)
    if (tid == 0) ast32(&p.pflags[s * FP], 1u);
  }
}

__global__ __launch_bounds__(256, 1) void lstm_main(KParams p)
{
  __shared__ __align__(16) char smem[64 * 656];   // L0 stage / L1 z-tile / producer buf / head
  __shared__ float cst[4352];                     // L0: [64][68]; L1: [2][32][68]
  __shared__ float biasl[64];
  const int wg = blockIdx.x;
  if (wg < 16)       run_l0(p, wg, smem, cst, biasl);
  else if (wg < 48)  run_l1(p, wg - 16, smem, cst, biasl);
  else               run_prod(p, wg - 48, smem);
}

// One-time: W1 x-part (rows 0..299, zero-pad to 320) -> bf16 fragment order.
__global__ void prep_w(KParams p) {
  int idx = blockIdx.x * 256 + threadIdx.x;
  if (idx >= 20 * 1024 * 16) return;
  int kk = idx & 15, n = (idx >> 4) & 1023, kt = idx >> 14;
  int k = kt * 16 + kk;
  int g = (n >> 4) & 3, su = n >> 6, u = n & 15;
  float v = (k < 300) ? p.W1[g][k * 256 + su * 16 + u] : 0.f;
  p.w1bf[idx] = (bf16_t)v;
}

// Zero tagged h rings + all flags (ws is re-poisoned before every launch).
// Zero tags = "step -1 valid with h=0", exactly the initial state.
__global__ void init_ws(u32* ws32) {
  int i = blockIdx.x * 256 + threadIdx.x;
  if (i < 214528) ws32[i] = 0u;   // [0, 858112): h1, h2, fl1, fl0g, pflags
}

extern "C" void kernel_launch(void* const* d_in, const int* in_sizes, int n_in,
                              void* d_out, int out_size, void* d_ws, size_t ws_size,
                              hipStream_t stream)
{
  KParams p;
  p.tok = (const int*)d_in[0];
  p.emb = (const float*)d_in[1];
  for (int g = 0; g < 4; ++g) {
    p.W1[g] = (const float*)d_in[2 + 2 * g];
    p.b1[g] = (const float*)d_in[3 + 2 * g];
    p.W2[g] = (const float*)d_in[10 + 2 * g];
    p.b2[g] = (const float*)d_in[11 + 2 * g];
  }
  p.Wd   = (const float*)d_in[18];
  p.bd   = (const float*)d_in[19];
  p.Wout = (const float*)d_in[20];
  p.bout = (const float*)d_in[21];
  p.out  = (float*)d_out;

  char* ws = (char*)d_ws;
  p.h1     = (u64*)ws;                    // 8 x 65536 B   -> 524288
  p.h2     = (u64*)(ws + 524288);         // 4 x 65536 B   -> 786432
  p.fl1    = (u32*)(ws + 786432);         // 32 x 128 B    -> 790528
  p.fl0g   = (u32*)(ws + 790528);         // 16 x 128 B    -> 792576
  p.pflags = (u32*)(ws + 792576);         // 512 x 128 B   -> 858112
  p.dstage = (float*)(ws + 858112);       // 32768 B       -> 890880
  p.w1bf   = (bf16_t*)(ws + 890880);      // 655360 B      -> 1546240
  p.gx     = (float*)(ws + 1546240);      // ring: R slabs of [64][1024] fp32

  long avail = (long)ws_size - 1546240L;
  int R = (int)(avail / 262144L);
  if (R > 64) R = 64;
  if (R < 1)  R = 1;
  p.R = R;

  hipLaunchKernelGGL(init_ws, dim3(838), dim3(256), 0, stream, (u32*)d_ws);
  hipLaunchKernelGGL(prep_w, dim3(1280), dim3(256), 0, stream, p);
  hipLaunchKernelGGL(lstm_main, dim3(16 + 32 + NPROD), dim3(256), 0, stream, p);
}